// Round 7
// baseline (217.278 us; speedup 1.0000x reference)
//
#include <hip/hip_runtime.h>

typedef _Float16 half8  __attribute__((ext_vector_type(8)));
typedef float    f32x4  __attribute__((ext_vector_type(4)));

__device__ __forceinline__ int swzp(int row) {
    return ((row ^ (row >> 3)) & 15) << 4;   // P region: 256B rows, 16B granules
}

// One WG = one (b,h,n) 128x128 attention block. 8 waves; wave w owns:
//   QK^T/softmax: q-rows [16w,16w+16);  PV: d-slab [16w,16w+16).
// LDS 64KB: K fp32 [128][512B] XOR-swizzled, filled by global_load_lds (no VGPR
// held by in-flight K -> ~64KB outstanding per WG; fixes the ~2.7TB/s MLP wall).
// P fp16 [128][256B] overlays [0,32K) after S2. V: 32 inline-asm dword loads
// (un-sinkable, un-crushable) issued after S2, consumed after S3.
__global__ __launch_bounds__(512, 4) void battn_kernel(
    const float* __restrict__ Q, const float* __restrict__ K,
    const float* __restrict__ V, float* __restrict__ O)
{
    __shared__ __align__(16) char smem[65536];
    const int tid  = threadIdx.x;
    const int lane = tid & 63;
    const int w    = tid >> 6;
    const int la   = lane & 15;
    const int u    = lane >> 4;
    const size_t base = (size_t)blockIdx.x * (128 * 128);

    const float* Qb = Q + base;
    const float* Kb = K + base;
    const float* Vb = V + base;
    float*       Ob = O + base;

    // ---- Q loads first (waited with vmcnt(8), K stays in flight) ----
    float4 qld[8];
    {
        const float* qrow = Qb + (w * 16 + la) * 128;
#pragma unroll
        for (int kk = 0; kk < 4; ++kk) {
            qld[2 * kk]     = *(const float4*)(qrow + kk * 32 + u * 8);
            qld[2 * kk + 1] = *(const float4*)(qrow + kk * 32 + u * 8 + 4);
        }
    }

    // ---- K -> LDS fp32 via global_load_lds, source pre-swizzled ----
    // Invariant: LDS[row*512 + x] = K[row][ (x ^ ((row&31)<<4)) / 4 ]
#pragma unroll
    for (int it = 0; it < 8; ++it) {
        const int dst  = (w * 8 + it) * 1024 + lane * 16;  // this lane's linear dest
        const int row  = dst >> 9;
        const int x    = dst & 511;
        const int srcf = row * 128 + ((x ^ ((row & 31) << 4)) >> 2);
        __builtin_amdgcn_global_load_lds(
            (const __attribute__((address_space(1))) void*)(Kb + srcf),
            (__attribute__((address_space(3))) void*)(smem + (w * 8 + it) * 1024),
            16, 0, 0);
    }

    // ---- Q fragments fp32->fp16 ----
    half8 qfrag[4];
#pragma unroll
    for (int kk = 0; kk < 4; ++kk) {
        const float4 a = qld[2 * kk];
        const float4 b = qld[2 * kk + 1];
        qfrag[kk][0] = (_Float16)a.x; qfrag[kk][1] = (_Float16)a.y;
        qfrag[kk][2] = (_Float16)a.z; qfrag[kk][3] = (_Float16)a.w;
        qfrag[kk][4] = (_Float16)b.x; qfrag[kk][5] = (_Float16)b.y;
        qfrag[kk][6] = (_Float16)b.z; qfrag[kk][7] = (_Float16)b.w;
    }

    __syncthreads();                                   // S1: K in LDS (vmcnt(0) drain)

    // ---------------- S = Q K^T (K fp32 in LDS, cvt at fragment build) ----------------
    f32x4 acc[8];
#pragma unroll
    for (int t = 0; t < 8; ++t) acc[t] = (f32x4){0.f, 0.f, 0.f, 0.f};
#pragma unroll
    for (int t = 0; t < 8; ++t) {
        const int row   = t * 16 + la;
        const int rbase = row * 512;
        const int sw    = (row & 31) << 4;
#pragma unroll
        for (int kk = 0; kk < 4; ++kk) {
            const int c0 = kk * 128 + u * 32;
            const float4 a = *(const float4*)(smem + rbase + (c0 ^ sw));
            const float4 b = *(const float4*)(smem + rbase + ((c0 + 16) ^ sw));
            half8 kf;
            kf[0] = (_Float16)a.x; kf[1] = (_Float16)a.y;
            kf[2] = (_Float16)a.z; kf[3] = (_Float16)a.w;
            kf[4] = (_Float16)b.x; kf[5] = (_Float16)b.y;
            kf[6] = (_Float16)b.z; kf[7] = (_Float16)b.w;
            acc[t] = __builtin_amdgcn_mfma_f32_16x16x32_f16(qfrag[kk], kf, acc[t], 0, 0, 0);
        }
    }
    // acc[t][r] = S[q-sub-row = 4u+r][col = 16t+la]

    // ---------------- row softmax (16 lanes sharing u hold one q-row) ----------------
    float inv[4];
#pragma unroll
    for (int r = 0; r < 4; ++r) {
        float m = acc[0][r];
#pragma unroll
        for (int t = 1; t < 8; ++t) m = fmaxf(m, acc[t][r]);
        m = fmaxf(m, __shfl_xor(m, 1));
        m = fmaxf(m, __shfl_xor(m, 2));
        m = fmaxf(m, __shfl_xor(m, 4));
        m = fmaxf(m, __shfl_xor(m, 8));
        float s = 0.f;
#pragma unroll
        for (int t = 0; t < 8; ++t) {
            const float e = __expf(acc[t][r] - m);
            acc[t][r] = e;
            s += e;
        }
        s += __shfl_xor(s, 1);
        s += __shfl_xor(s, 2);
        s += __shfl_xor(s, 4);
        s += __shfl_xor(s, 8);
        inv[r] = 1.0f / s;
    }

    __syncthreads();                                   // S2: all K reads done

    // ---- V loads via inline asm (forced issue here; land during P-write) ----
    // lane (la,u) needs V[j = kk*32 + u*8 + i][d = 16w + la]
    float vld[32];
    {
        const float* vbase = Vb + w * 16 + la;
#pragma unroll
        for (int kk = 0; kk < 4; ++kk)
#pragma unroll
            for (int i = 0; i < 8; ++i) {
                const float* p = vbase + (kk * 32 + u * 8 + i) * 128;
                asm volatile("global_load_dword %0, %1, off"
                             : "=v"(vld[kk * 8 + i]) : "v"(p));
            }
    }

    // ---------------- P -> LDS fp16 (overlay K region), acc dies here ----------------
#pragma unroll
    for (int t = 0; t < 8; ++t) {
#pragma unroll
        for (int r = 0; r < 4; ++r) {
            const int q   = w * 16 + u * 4 + r;        // global q row
            const int col = t * 16 + la;               // j
            int byte = q * 256 + col * 2;
            byte ^= swzp(q & 15);
            *(_Float16*)(smem + byte) = (_Float16)(acc[t][r] * inv[r]);
        }
    }
    __syncthreads();                                   // S3: P staged

    asm volatile("s_waitcnt vmcnt(0)" ::: "memory");   // V results valid (asm loads)
    __builtin_amdgcn_sched_barrier(0);                 // rule #18: no hoist past waitcnt

    half8 vfrag[4];
#pragma unroll
    for (int kk = 0; kk < 4; ++kk)
#pragma unroll
        for (int i = 0; i < 8; ++i)
            vfrag[kk][i] = (_Float16)vld[kk * 8 + i];

    // ---------------- O^T = V^T P^T : A = V-frag (m=d), B = P-frag (n=q) ----------------
#pragma unroll
    for (int qt = 0; qt < 8; ++qt) {
        half8 pb[4];
#pragma unroll
        for (int kk = 0; kk < 4; ++kk) {
            int byte = (qt * 16 + la) * 256 + kk * 64 + u * 16;
            byte ^= swzp(la);
            pb[kk] = *(const half8*)(smem + byte);
        }
        f32x4 oa = (f32x4){0.f, 0.f, 0.f, 0.f};
#pragma unroll
        for (int kk = 0; kk < 4; ++kk)
            oa = __builtin_amdgcn_mfma_f32_16x16x32_f16(vfrag[kk], pb[kk], oa, 0, 0, 0);
        // lane holds O[q = qt*16+la][d = 16w + 4u + r], r=0..3 -> contiguous float4
        *(float4*)(Ob + (qt * 16 + la) * 128 + w * 16 + u * 4) =
            make_float4(oa[0], oa[1], oa[2], oa[3]);
    }
}

extern "C" void kernel_launch(void* const* d_in, const int* in_sizes, int n_in,
                              void* d_out, int out_size, void* d_ws, size_t ws_size,
                              hipStream_t stream) {
    const float* q = (const float*)d_in[0];
    const float* k = (const float*)d_in[1];
    const float* v = (const float*)d_in[2];
    float* o = (float*)d_out;
    const int nblocks = in_sizes[0] / (128 * 128);   // 4096
    battn_kernel<<<dim3(nblocks), dim3(512), 0, stream>>>(q, k, v, o);
}